// Round 3
// baseline (2113.034 us; speedup 1.0000x reference)
//
#include <hip/hip_runtime.h>
#include <math.h>

#define NA 50000
#define NP 1000000
#define FD 128
#define KD 64
#define NB 5
#define NRI_ 3
#define NRF_ 2

typedef short short8_t __attribute__((ext_vector_type(8)));
typedef short short4_t __attribute__((ext_vector_type(4)));
typedef float f32x4 __attribute__((ext_vector_type(4)));

// fast shifted-softplus: max(x,0) + log(1+exp(-|x|)) - ln2, native v_exp/v_log
__device__ __forceinline__ float sspf(float x) {
    float t = __logf(__expf(-fabsf(x)) + 1.0f);
    return fmaxf(x, 0.0f) + (t - 0.69314718055994530942f);
}

// hardware packed f32->bf16 (RNE)
__device__ __forceinline__ unsigned cvt_pk_bf16(float lo, float hi) {
    unsigned r;
    asm("v_cvt_pk_bf16_f32 %0, %1, %2" : "=v"(r) : "v"(lo), "v"(hi));
    return r;
}

__device__ __forceinline__ short f2bf(float f) {
    unsigned r;
    asm("v_cvt_pk_bf16_f32 %0, %1, %1" : "=v"(r) : "v"(f));
    return (short)r;
}

// One block per matrix: src [K][128] f32 -> dst [128][K] bf16 (transposed)
__global__ void transpose_weights(const float* __restrict__ src,
                                  short* __restrict__ dst, int K)
{
    const size_t mo = (size_t)blockIdx.x * K * 128;
    const float* s = src + mo;
    short* d = dst + mo;
    for (int e = threadIdx.x; e < K * 128; e += 256) {
        int k = e >> 7, n = e & 127;
        d[n * K + k] = f2bf(s[e]);
    }
}

// one-time: desc[p][k] = bf16(cutoff[p] * rbf[p][k]); 8 elems per thread
__global__ void prep_desc(const float* __restrict__ rbfs,
                          const float* __restrict__ cutoffs,
                          short* __restrict__ desc)
{
    long long c = (long long)blockIdx.x * 256 + threadIdx.x;   // 8-elem chunk id
    if (c >= (long long)NP * 8) return;
    long long pair = c >> 3;
    float cu = cutoffs[pair];
    const float* s = rbfs + c * 8;
    float4 a = *(const float4*)s;
    float4 b = *(const float4*)(s + 4);
    int4 pk;
    pk.x = (int)cvt_pk_bf16(a.x * cu, a.y * cu);
    pk.y = (int)cvt_pk_bf16(a.z * cu, a.w * cu);
    pk.z = (int)cvt_pk_bf16(b.x * cu, b.y * cu);
    pk.w = (int)cvt_pk_bf16(b.z * cu, b.w * cu);
    *(int4*)&desc[c * 8] = pk;
}

// stage one [128 n][128 k] bf16 weight into wt_s [128][136]
__device__ __forceinline__ void stage_wt(const short* __restrict__ WT,
                                         short* wt_s, int tid)
{
#pragma unroll
    for (int i = 0; i < 8; ++i) {
        int c = i * 256 + tid;
        int n = c >> 4, kc = c & 15;
        *(short8_t*)&wt_s[n * 136 + kc * 8] = *(const short8_t*)&WT[n * 128 + kc * 8];
    }
}

// acc += actw(16 rows bf16) @ wt_s(128x128 bf16)
__device__ __forceinline__ void gemm16(const short* actw, const short* wt_s,
                                       int mI, int quad, f32x4 acc[8])
{
#pragma unroll
    for (int ch = 0; ch < 4; ++ch) {
        short8_t a = *(const short8_t*)&actw[mI * 136 + ch * 32 + quad * 8];
#pragma unroll
        for (int ct = 0; ct < 8; ++ct) {
            short8_t bf = *(const short8_t*)&wt_s[(ct * 16 + mI) * 136 + ch * 32 + quad * 8];
            acc[ct] = __builtin_amdgcn_mfma_f32_16x16x32_bf16(a, bf, acc[ct], 0, 0, 0);
        }
    }
}

// xi = ssp(ssp(x)@Wi + bi), xj = ssp(ssp(x)@Wj + bj)   (only used for b=0)
__launch_bounds__(256, 3)
__global__ void pre_kernel(const float* __restrict__ x,
                           const short* __restrict__ WiT, const float* __restrict__ bi_,
                           const short* __restrict__ WjT, const float* __restrict__ bj_,
                           float* __restrict__ xi_out, float* __restrict__ xj_out)
{
    __shared__ short act_s[64 * 136];
    __shared__ short wt_s[128 * 136];
    const int tid = threadIdx.x;
    const int lane = tid & 63, wv = tid >> 6;
    const int mI = lane & 15, quad = lane >> 4;
    const short* actw = act_s + wv * 16 * 136;
    const int row0 = blockIdx.x * 64;
    const int rowrd = row0 + wv * 16 + quad * 4;

#pragma unroll
    for (int i = 0; i < 8; ++i) {
        int f = i * 256 + tid;
        int rr = f >> 5;
        int c4 = (f & 31) * 4;
        float4 v = make_float4(0.f, 0.f, 0.f, 0.f);
        if (row0 + rr < NA) v = *(const float4*)&x[(size_t)(row0 + rr) * FD + c4];
        int2 pk;
        pk.x = (int)cvt_pk_bf16(sspf(v.x), sspf(v.y));
        pk.y = (int)cvt_pk_bf16(sspf(v.z), sspf(v.w));
        *(int2*)&act_s[rr * 136 + c4] = pk;
    }
    stage_wt(WiT, wt_s, tid);
    __syncthreads();

    f32x4 acc[8];
#pragma unroll
    for (int ct = 0; ct < 8; ++ct) acc[ct] = (f32x4){0.f, 0.f, 0.f, 0.f};
    gemm16(actw, wt_s, mI, quad, acc);
#pragma unroll
    for (int ct = 0; ct < 8; ++ct) {
        float bb = bi_[ct * 16 + mI];
#pragma unroll
        for (int rg = 0; rg < 4; ++rg) {
            int r = rowrd + rg;
            if (r < NA) xi_out[(size_t)r * FD + ct * 16 + mI] = sspf(acc[ct][rg] + bb);
        }
    }
    __syncthreads();
    stage_wt(WjT, wt_s, tid);
    __syncthreads();
#pragma unroll
    for (int ct = 0; ct < 8; ++ct) acc[ct] = (f32x4){0.f, 0.f, 0.f, 0.f};
    gemm16(actw, wt_s, mI, quad, acc);
#pragma unroll
    for (int ct = 0; ct < 8; ++ct) {
        float bb = bj_[ct * 16 + mI];
#pragma unroll
        for (int rg = 0; rg < 4; ++rg) {
            int r = rowrd + rg;
            if (r < NA) xj_out[(size_t)r * FD + ct * 16 + mI] = sspf(acc[ct][rg] + bb);
        }
    }
}

// whole post-scatter atom chain; TAIL: also compute xi/xj of the NEXT block
// from xreg (fuses pre_kernel of block b+1 — x never leaves registers).
template<bool TAIL>
__launch_bounds__(256, 3)
__global__ void chain_kernel(const float* __restrict__ xprev,
                             const float* __restrict__ mbuf,
                             const short* __restrict__ Wr1T, const float* __restrict__ br1_,
                             const short* __restrict__ Wr2T, const float* __restrict__ br2_,
                             const short* __restrict__ WoT,  const float* __restrict__ bo_,
                             const float* __restrict__ u_,
                             const short* __restrict__ Wf1T, const float* __restrict__ bf1_,
                             const short* __restrict__ Wf2T, const float* __restrict__ bf2_,
                             float* __restrict__ xout,
                             const short* __restrict__ WiT, const float* __restrict__ bi_,
                             const short* __restrict__ WjT, const float* __restrict__ bj_,
                             float* __restrict__ xi_out, float* __restrict__ xj_out)
{
    __shared__ short act_s[64 * 136];
    __shared__ short wt_s[128 * 136];
    const int tid = threadIdx.x;
    const int lane = tid & 63, wv = tid >> 6;
    const int mI = lane & 15, quad = lane >> 4;
    short* actw = act_s + wv * 16 * 136;
    const int rowrd = blockIdx.x * 64 + wv * 16 + quad * 4;

    float mreg[8][4];
#pragma unroll
    for (int ct = 0; ct < 8; ++ct)
#pragma unroll
        for (int rg = 0; rg < 4; ++rg) {
            int r = rowrd + rg;
            mreg[ct][rg] = (r < NA) ? mbuf[(size_t)r * FD + ct * 16 + mI] : 0.f;
        }

    f32x4 acc[8];

    // ---- interaction residuals ----
    for (int r = 0; r < NRI_; ++r) {
        __syncthreads();
        stage_wt(Wr1T + (size_t)r * FD * FD, wt_s, tid);
#pragma unroll
        for (int ct = 0; ct < 8; ++ct)
#pragma unroll
            for (int rg = 0; rg < 4; ++rg)
                actw[(quad * 4 + rg) * 136 + ct * 16 + mI] = f2bf(sspf(mreg[ct][rg]));
        __syncthreads();
#pragma unroll
        for (int ct = 0; ct < 8; ++ct) acc[ct] = (f32x4){0.f, 0.f, 0.f, 0.f};
        gemm16(actw, wt_s, mI, quad, acc);

        __syncthreads();
        stage_wt(Wr2T + (size_t)r * FD * FD, wt_s, tid);
#pragma unroll
        for (int ct = 0; ct < 8; ++ct) {
            float b1 = br1_[r * FD + ct * 16 + mI];
#pragma unroll
            for (int rg = 0; rg < 4; ++rg)
                actw[(quad * 4 + rg) * 136 + ct * 16 + mI] = f2bf(sspf(acc[ct][rg] + b1));
        }
        __syncthreads();
#pragma unroll
        for (int ct = 0; ct < 8; ++ct) acc[ct] = (f32x4){0.f, 0.f, 0.f, 0.f};
        gemm16(actw, wt_s, mI, quad, acc);
#pragma unroll
        for (int ct = 0; ct < 8; ++ct) {
            float b2 = br2_[r * FD + ct * 16 + mI];
#pragma unroll
            for (int rg = 0; rg < 4; ++rg)
                mreg[ct][rg] += acc[ct][rg] + b2;
        }
    }

    // ---- gated update ----
    __syncthreads();
    stage_wt(WoT, wt_s, tid);
#pragma unroll
    for (int ct = 0; ct < 8; ++ct)
#pragma unroll
        for (int rg = 0; rg < 4; ++rg)
            actw[(quad * 4 + rg) * 136 + ct * 16 + mI] = f2bf(sspf(mreg[ct][rg]));
    __syncthreads();
#pragma unroll
    for (int ct = 0; ct < 8; ++ct) acc[ct] = (f32x4){0.f, 0.f, 0.f, 0.f};
    gemm16(actw, wt_s, mI, quad, acc);

    float xreg[8][4];
#pragma unroll
    for (int ct = 0; ct < 8; ++ct) {
        float bo = bo_[ct * 16 + mI];
        float uu = u_[ct * 16 + mI];
#pragma unroll
        for (int rg = 0; rg < 4; ++rg) {
            int r = rowrd + rg;
            float xp = (r < NA) ? xprev[(size_t)r * FD + ct * 16 + mI] : 0.f;
            xreg[ct][rg] = fmaf(uu, xp, acc[ct][rg] + bo);
        }
    }

    // ---- feature residuals ----
    for (int r = 0; r < NRF_; ++r) {
        __syncthreads();
        stage_wt(Wf1T + (size_t)r * FD * FD, wt_s, tid);
#pragma unroll
        for (int ct = 0; ct < 8; ++ct)
#pragma unroll
            for (int rg = 0; rg < 4; ++rg)
                actw[(quad * 4 + rg) * 136 + ct * 16 + mI] = f2bf(sspf(xreg[ct][rg]));
        __syncthreads();
#pragma unroll
        for (int ct = 0; ct < 8; ++ct) acc[ct] = (f32x4){0.f, 0.f, 0.f, 0.f};
        gemm16(actw, wt_s, mI, quad, acc);

        __syncthreads();
        stage_wt(Wf2T + (size_t)r * FD * FD, wt_s, tid);
#pragma unroll
        for (int ct = 0; ct < 8; ++ct) {
            float b1 = bf1_[r * FD + ct * 16 + mI];
#pragma unroll
            for (int rg = 0; rg < 4; ++rg)
                actw[(quad * 4 + rg) * 136 + ct * 16 + mI] = f2bf(sspf(acc[ct][rg] + b1));
        }
        __syncthreads();
#pragma unroll
        for (int ct = 0; ct < 8; ++ct) acc[ct] = (f32x4){0.f, 0.f, 0.f, 0.f};
        gemm16(actw, wt_s, mI, quad, acc);
#pragma unroll
        for (int ct = 0; ct < 8; ++ct) {
            float b2 = bf2_[r * FD + ct * 16 + mI];
#pragma unroll
            for (int rg = 0; rg < 4; ++rg)
                xreg[ct][rg] += acc[ct][rg] + b2;
        }
    }

#pragma unroll
    for (int ct = 0; ct < 8; ++ct)
#pragma unroll
        for (int rg = 0; rg < 4; ++rg) {
            int r = rowrd + rg;
            if (r < NA) xout[(size_t)r * FD + ct * 16 + mI] = xreg[ct][rg];
        }

    // ---- fused pre of next block: xi=ssp(ssp(x)@Wi+bi), xj=ssp(ssp(x)@Wj+bj) ----
    if constexpr (TAIL) {
        __syncthreads();
        stage_wt(WiT, wt_s, tid);
#pragma unroll
        for (int ct = 0; ct < 8; ++ct)
#pragma unroll
            for (int rg = 0; rg < 4; ++rg)
                actw[(quad * 4 + rg) * 136 + ct * 16 + mI] = f2bf(sspf(xreg[ct][rg]));
        __syncthreads();
#pragma unroll
        for (int ct = 0; ct < 8; ++ct) acc[ct] = (f32x4){0.f, 0.f, 0.f, 0.f};
        gemm16(actw, wt_s, mI, quad, acc);
#pragma unroll
        for (int ct = 0; ct < 8; ++ct) {
            float bb = bi_[ct * 16 + mI];
#pragma unroll
            for (int rg = 0; rg < 4; ++rg) {
                int r = rowrd + rg;
                if (r < NA) xi_out[(size_t)r * FD + ct * 16 + mI] = sspf(acc[ct][rg] + bb);
            }
        }
        __syncthreads();                 // all waves done with wt_s (act unchanged)
        stage_wt(WjT, wt_s, tid);
        __syncthreads();
#pragma unroll
        for (int ct = 0; ct < 8; ++ct) acc[ct] = (f32x4){0.f, 0.f, 0.f, 0.f};
        gemm16(actw, wt_s, mI, quad, acc);
#pragma unroll
        for (int ct = 0; ct < 8; ++ct) {
            float bb = bj_[ct * 16 + mI];
#pragma unroll
            for (int rg = 0; rg < 4; ++rg) {
                int r = rowrd + rg;
                if (r < NA) xj_out[(size_t)r * FD + ct * 16 + mI] = sspf(acc[ct][rg] + bb);
            }
        }
    }
}

// g = desc @ Wg (MFMA) ; msg = g * xj[idx_j] ; segment-sum into m
template<bool DESC>
__launch_bounds__(256, 4)
__global__ void pair_mfma(const float* __restrict__ rbfs,
                          const float* __restrict__ cutoffs,
                          const short* __restrict__ desc,   // [NP][64] bf16 (if DESC)
                          const int* __restrict__ idx_i,
                          const int* __restrict__ idx_j,
                          const short* __restrict__ WgT,    // [128 n][64 k] bf16
                          const float* __restrict__ xj,
                          float* __restrict__ mout)
{
    __shared__ float g_s[64 * 132];          // 33792 B; aliased as wt_s during MFMA
    __shared__ int ii_s[128];
    __shared__ int jj_s[128];
    short* wt_s = (short*)g_s;               // [128 n][72 k] = 18432 B

    const int tid = threadIdx.x;
    const long long p0 = (long long)blockIdx.x * 128;

#pragma unroll
    for (int i = 0; i < 4; ++i) {
        int c = i * 256 + tid;
        int n = c >> 3, kc = c & 7;
        *(short8_t*)&wt_s[n * 72 + kc * 8] = *(const short8_t*)&WgT[n * 64 + kc * 8];
    }
    if (tid < 128) {
        long long pg = p0 + tid;
        ii_s[tid] = (pg < NP) ? idx_i[pg] : -1;
        jj_s[tid] = (pg < NP) ? idx_j[pg] : 0;
    }
    __syncthreads();

    const int lane = tid & 63, wv = tid >> 6;
    const int m = lane & 15, quad = lane >> 4;

    f32x4 acc[2][8];
#pragma unroll
    for (int rt = 0; rt < 2; ++rt)
#pragma unroll
        for (int ct = 0; ct < 8; ++ct) acc[rt][ct] = (f32x4){0.f, 0.f, 0.f, 0.f};

#pragma unroll
    for (int chunk = 0; chunk < 2; ++chunk) {
        short8_t afr[2];
#pragma unroll
        for (int rt = 0; rt < 2; ++rt) {
            long long pg = p0 + wv * 32 + rt * 16 + m;
            if constexpr (DESC) {
                if (pg < NP) {
                    afr[rt] = *(const short8_t*)&desc[pg * KD + chunk * 32 + quad * 8];
                } else {
                    int4 z = make_int4(0, 0, 0, 0);
                    afr[rt] = __builtin_bit_cast(short8_t, z);
                }
            } else {
                float v[8];
                if (pg < NP) {
                    const float* ap = rbfs + pg * KD + chunk * 32 + quad * 8;
                    float4 x0 = *(const float4*)ap;
                    float4 x1 = *(const float4*)(ap + 4);
                    float cu = cutoffs[pg];
                    v[0] = x0.x * cu; v[1] = x0.y * cu; v[2] = x0.z * cu; v[3] = x0.w * cu;
                    v[4] = x1.x * cu; v[5] = x1.y * cu; v[6] = x1.z * cu; v[7] = x1.w * cu;
                } else {
#pragma unroll
                    for (int j = 0; j < 8; ++j) v[j] = 0.f;
                }
                int4 pk = make_int4((int)cvt_pk_bf16(v[0], v[1]),
                                    (int)cvt_pk_bf16(v[2], v[3]),
                                    (int)cvt_pk_bf16(v[4], v[5]),
                                    (int)cvt_pk_bf16(v[6], v[7]));
                afr[rt] = __builtin_bit_cast(short8_t, pk);
            }
        }
#pragma unroll
        for (int ct = 0; ct < 8; ++ct) {
            short8_t bfr = *(short8_t*)&wt_s[(ct * 16 + m) * 72 + chunk * 32 + quad * 8];
            acc[0][ct] = __builtin_amdgcn_mfma_f32_16x16x32_bf16(afr[0], bfr, acc[0][ct], 0, 0, 0);
            acc[1][ct] = __builtin_amdgcn_mfma_f32_16x16x32_bf16(afr[1], bfr, acc[1][ct], 0, 0, 0);
        }
    }
    __syncthreads();                         // everyone done reading wt_s

    const int tx = tid & 15, ty = tid >> 4;
    const int c0 = tx * 4, c1 = c0 + 64;
    const int col = tid & 127, sh = tid >> 7;

#pragma unroll
    for (int h = 0; h < 2; ++h) {
        if ((wv >> 1) == h) {
#pragma unroll
            for (int ct = 0; ct < 8; ++ct) {
                int cg = ct * 16 + m;
#pragma unroll
                for (int rt = 0; rt < 2; ++rt) {
                    int lp = (wv & 1) * 32 + rt * 16 + quad * 4;
#pragma unroll
                    for (int rg = 0; rg < 4; ++rg)
                        g_s[(lp + rg) * 132 + cg] = acc[rt][ct][rg];
                }
            }
        }
        __syncthreads();
#pragma unroll
        for (int i = 0; i < 4; ++i) {
            int p = ty + 16 * i;
            int jrow = jj_s[h * 64 + p];
            float4 xa = *(const float4*)&xj[(size_t)jrow * FD + c0];
            float4 xb = *(const float4*)&xj[(size_t)jrow * FD + c1];
            float4 ga = *(float4*)&g_s[p * 132 + c0];
            float4 gb = *(float4*)&g_s[p * 132 + c1];
            ga.x *= xa.x; ga.y *= xa.y; ga.z *= xa.z; ga.w *= xa.w;
            gb.x *= xb.x; gb.y *= xb.y; gb.z *= xb.z; gb.w *= xb.w;
            *(float4*)&g_s[p * 132 + c0] = ga;
            *(float4*)&g_s[p * 132 + c1] = gb;
        }
        __syncthreads();
        {
            int base = h * 64 + sh * 32;
            float accum = 0.f;
            int cur = ii_s[base];
            for (int q = 0; q < 32; ++q) {
                int a = ii_s[base + q];
                if (a != cur) {
                    if (cur >= 0) atomicAdd(&mout[(size_t)cur * FD + col], accum);
                    accum = 0.f;
                    cur = a;
                }
                accum += g_s[(sh * 32 + q) * 132 + col];
            }
            if (cur >= 0) atomicAdd(&mout[(size_t)cur * FD + col], accum);
        }
        if (h == 0) __syncthreads();
    }
}

extern "C" void kernel_launch(void* const* d_in, const int* in_sizes, int n_in,
                              void* d_out, int out_size, void* d_ws, size_t ws_size,
                              hipStream_t stream)
{
    const float* features = (const float*)d_in[0];
    const float* cutoffs  = (const float*)d_in[1];
    const float* rbfs     = (const float*)d_in[2];
    const int*   idx_i    = (const int*)d_in[3];
    const int*   idx_j    = (const int*)d_in[4];
    const float* Wg   = (const float*)d_in[5];
    const float* Wi   = (const float*)d_in[6];
    const float* bi   = (const float*)d_in[7];
    const float* Wj   = (const float*)d_in[8];
    const float* bj   = (const float*)d_in[9];
    const float* Wr1  = (const float*)d_in[10];
    const float* br1  = (const float*)d_in[11];
    const float* Wr2  = (const float*)d_in[12];
    const float* br2  = (const float*)d_in[13];
    const float* Wout = (const float*)d_in[14];
    const float* bout = (const float*)d_in[15];
    const float* u    = (const float*)d_in[16];
    const float* Wf1  = (const float*)d_in[17];
    const float* bf1  = (const float*)d_in[18];
    const float* Wf2  = (const float*)d_in[19];
    const float* bf2  = (const float*)d_in[20];
    float* out = (float*)d_out;

    const size_t NF = (size_t)NA * FD;
    const size_t MS = (size_t)FD * FD;
    float* mbuf = (float*)d_ws;
    short* wtb  = (short*)(mbuf + NF);
    short* wgt  = wtb + 65 * MS;
    short* desc = wgt + (size_t)NB * FD * KD;
    float* xjbuf = out + 4 * NF;            // out[4] slice: free until b=4's chain write

    const size_t base_bytes = NF * 4 + 65 * MS * 2 + (size_t)NB * FD * KD * 2;
    const size_t desc_bytes = (size_t)NP * KD * 2;
    const bool use_desc = ws_size >= base_bytes + desc_bytes;

    transpose_weights<<<5,  256, 0, stream>>>(Wi,   wtb +  0 * MS, 128);
    transpose_weights<<<5,  256, 0, stream>>>(Wj,   wtb +  5 * MS, 128);
    transpose_weights<<<15, 256, 0, stream>>>(Wr1,  wtb + 10 * MS, 128);
    transpose_weights<<<15, 256, 0, stream>>>(Wr2,  wtb + 25 * MS, 128);
    transpose_weights<<<5,  256, 0, stream>>>(Wout, wtb + 40 * MS, 128);
    transpose_weights<<<10, 256, 0, stream>>>(Wf1,  wtb + 45 * MS, 128);
    transpose_weights<<<10, 256, 0, stream>>>(Wf2,  wtb + 55 * MS, 128);
    transpose_weights<<<5,  256, 0, stream>>>(Wg,   wgt, 64);
    if (use_desc) {
        prep_desc<<<(int)(((long long)NP * 8 + 255) / 256), 256, 0, stream>>>(rbfs, cutoffs, desc);
    }

    const int gA = (NA + 63) / 64;          // 782
    const int gP = (NP + 127) / 128;        // 7813
    dim3 blk(256);

    // b = 0: standalone pre (x = features)
    pre_kernel<<<gA, blk, 0, stream>>>(features,
        wtb + 0 * MS, bi, wtb + 5 * MS, bj, mbuf, xjbuf);

    const float* x = features;
    for (int b = 0; b < NB; ++b) {
        float* xout = out + (size_t)b * NF;

        if (use_desc) {
            pair_mfma<true><<<gP, blk, 0, stream>>>(rbfs, cutoffs, desc, idx_i, idx_j,
                wgt + (size_t)b * FD * KD, xjbuf, mbuf);
        } else {
            pair_mfma<false><<<gP, blk, 0, stream>>>(rbfs, cutoffs, desc, idx_i, idx_j,
                wgt + (size_t)b * FD * KD, xjbuf, mbuf);
        }

        if (b < NB - 1) {
            // fused: chain(b) + pre(b+1) from in-register xreg
            chain_kernel<true><<<gA, blk, 0, stream>>>(x, mbuf,
                wtb + (10 + b * NRI_) * MS, br1 + (size_t)b * NRI_ * FD,
                wtb + (25 + b * NRI_) * MS, br2 + (size_t)b * NRI_ * FD,
                wtb + (40 + b) * MS, bout + (size_t)b * FD, u + (size_t)b * FD,
                wtb + (45 + b * NRF_) * MS, bf1 + (size_t)b * NRF_ * FD,
                wtb + (55 + b * NRF_) * MS, bf2 + (size_t)b * NRF_ * FD,
                xout,
                wtb + (0 + (b + 1)) * MS, bi + (size_t)(b + 1) * FD,
                wtb + (5 + (b + 1)) * MS, bj + (size_t)(b + 1) * FD,
                mbuf, xjbuf);
        } else {
            chain_kernel<false><<<gA, blk, 0, stream>>>(x, mbuf,
                wtb + (10 + b * NRI_) * MS, br1 + (size_t)b * NRI_ * FD,
                wtb + (25 + b * NRI_) * MS, br2 + (size_t)b * NRI_ * FD,
                wtb + (40 + b) * MS, bout + (size_t)b * FD, u + (size_t)b * FD,
                wtb + (45 + b * NRF_) * MS, bf1 + (size_t)b * NRF_ * FD,
                wtb + (55 + b * NRF_) * MS, bf2 + (size_t)b * NRF_ * FD,
                xout,
                (const short*)nullptr, (const float*)nullptr,
                (const short*)nullptr, (const float*)nullptr,
                (float*)nullptr, (float*)nullptr);
        }
        x = xout;
    }
}

// Round 4
// 1805.824 us; speedup vs baseline: 1.1701x; 1.1701x over previous
//
#include <hip/hip_runtime.h>
#include <math.h>

#define NA 50000
#define NP 1000000
#define FD 128
#define KD 64
#define NB 5
#define NRI_ 3
#define NRF_ 2

typedef short short8_t __attribute__((ext_vector_type(8)));
typedef float f32x4 __attribute__((ext_vector_type(4)));

// fast shifted-softplus: max(x,0) + log(1+exp(-|x|)) - ln2, native v_exp/v_log
__device__ __forceinline__ float sspf(float x) {
    float t = __logf(__expf(-fabsf(x)) + 1.0f);
    return fmaxf(x, 0.0f) + (t - 0.69314718055994530942f);
}

// hardware packed f32->bf16 (RNE)
__device__ __forceinline__ unsigned cvt_pk_bf16(float lo, float hi) {
    unsigned r;
    asm("v_cvt_pk_bf16_f32 %0, %1, %2" : "=v"(r) : "v"(lo), "v"(hi));
    return r;
}

__device__ __forceinline__ short f2bf(float f) {
    unsigned r;
    asm("v_cvt_pk_bf16_f32 %0, %1, %1" : "=v"(r) : "v"(f));
    return (short)r;
}

// MFMA-fragment-order weight transform (one block per matrix).
// dst[((ch*8+ct)*64 + lane)*8 + j] = W[k=ch*32+(lane>>4)*8+j][n=ct*16+(lane&15)]
// src layout [K][128] row-major; kch = K/32 (4 for 128x128, 2 for Wg 64x128).
__global__ void frag_weights(const float* __restrict__ src,
                             short* __restrict__ dst, int kch)
{
    const int nchunk = kch * 512;
    const float* s = src + (size_t)blockIdx.x * kch * 4096;
    short* d = dst + (size_t)blockIdx.x * kch * 4096;
    for (int c = threadIdx.x; c < nchunk; c += 256) {
        int lane = c & 63, ct = (c >> 6) & 7, ch = c >> 9;
        int quad = lane >> 4, mI = lane & 15;
        const float* sp = s + (ch * 32 + quad * 8) * 128 + ct * 16 + mI;
        float v[8];
#pragma unroll
        for (int j = 0; j < 8; ++j) v[j] = sp[j * 128];
        int4 pk = make_int4((int)cvt_pk_bf16(v[0], v[1]),
                            (int)cvt_pk_bf16(v[2], v[3]),
                            (int)cvt_pk_bf16(v[4], v[5]),
                            (int)cvt_pk_bf16(v[6], v[7]));
        *(short8_t*)&d[c * 8] = __builtin_bit_cast(short8_t, pk);
    }
}

// one-time: descF in A-fragment order per 16-pair tile:
// descF[((t16*2+chunk)*64+lane)*8+j] = bf16(cutoff[p]*rbf[p][chunk*32+(lane>>4)*8+j]), p=t16*16+(lane&15)
__global__ void prep_desc(const float* __restrict__ rbfs,
                          const float* __restrict__ cutoffs,
                          short* __restrict__ descF)
{
    long long c = (long long)blockIdx.x * 256 + threadIdx.x;   // short8 chunk id
    if (c >= (long long)NP * 8) return;
    int lane = (int)(c & 63);
    int chunk = (int)((c >> 6) & 1);
    long long t16 = c >> 7;
    int quad = lane >> 4, mI = lane & 15;
    long long p = t16 * 16 + mI;                 // NP % 16 == 0 -> always < NP
    float cu = cutoffs[p];
    const float* s = rbfs + p * KD + chunk * 32 + quad * 8;
    float4 a = *(const float4*)s;
    float4 b = *(const float4*)(s + 4);
    int4 pk;
    pk.x = (int)cvt_pk_bf16(a.x * cu, a.y * cu);
    pk.y = (int)cvt_pk_bf16(a.z * cu, a.w * cu);
    pk.z = (int)cvt_pk_bf16(b.x * cu, b.y * cu);
    pk.w = (int)cvt_pk_bf16(b.z * cu, b.w * cu);
    *(short8_t*)&descF[c * 8] = __builtin_bit_cast(short8_t, pk);
}

// acc += actw(16 rows bf16, wave-private LDS) @ WF(frag-order global, L2-hot)
__device__ __forceinline__ void gemm16_direct(const short* actw,
                                              const short* __restrict__ WF,
                                              int mI, int quad, int lane,
                                              f32x4 acc[8])
{
#pragma unroll
    for (int ch = 0; ch < 4; ++ch) {
        short8_t a = *(const short8_t*)&actw[mI * 136 + ch * 32 + quad * 8];
#pragma unroll
        for (int ct = 0; ct < 8; ++ct) {
            short8_t bf = *(const short8_t*)&WF[((ch * 8 + ct) * 64 + lane) * 8];
            acc[ct] = __builtin_amdgcn_mfma_f32_16x16x32_bf16(a, bf, acc[ct], 0, 0, 0);
        }
    }
}

// xi = ssp(ssp(x)@Wi + bi), xj = ssp(ssp(x)@Wj + bj)   (b=0 only); one barrier total
__launch_bounds__(256, 4)
__global__ void pre_kernel(const float* __restrict__ x,
                           const short* __restrict__ WiF, const float* __restrict__ bi_,
                           const short* __restrict__ WjF, const float* __restrict__ bj_,
                           float* __restrict__ xi_out, float* __restrict__ xj_out)
{
    __shared__ short act_s[64 * 136];
    const int tid = threadIdx.x;
    const int lane = tid & 63, wv = tid >> 6;
    const int mI = lane & 15, quad = lane >> 4;
    const short* actw = act_s + wv * 16 * 136;
    const int row0 = blockIdx.x * 64;
    const int rowrd = row0 + wv * 16 + quad * 4;

#pragma unroll
    for (int i = 0; i < 8; ++i) {
        int f = i * 256 + tid;
        int rr = f >> 5;
        int c4 = (f & 31) * 4;
        float4 v = make_float4(0.f, 0.f, 0.f, 0.f);
        if (row0 + rr < NA) v = *(const float4*)&x[(size_t)(row0 + rr) * FD + c4];
        int2 pk;
        pk.x = (int)cvt_pk_bf16(sspf(v.x), sspf(v.y));
        pk.y = (int)cvt_pk_bf16(sspf(v.z), sspf(v.w));
        *(int2*)&act_s[rr * 136 + c4] = pk;
    }
    __syncthreads();                      // cross-wave act stage -> the only barrier

    f32x4 acc[8];
#pragma unroll
    for (int ct = 0; ct < 8; ++ct) acc[ct] = (f32x4){0.f, 0.f, 0.f, 0.f};
    gemm16_direct(actw, WiF, mI, quad, lane, acc);
#pragma unroll
    for (int ct = 0; ct < 8; ++ct) {
        float bb = bi_[ct * 16 + mI];
#pragma unroll
        for (int rg = 0; rg < 4; ++rg) {
            int r = rowrd + rg;
            if (r < NA) xi_out[(size_t)r * FD + ct * 16 + mI] = sspf(acc[ct][rg] + bb);
        }
    }
#pragma unroll
    for (int ct = 0; ct < 8; ++ct) acc[ct] = (f32x4){0.f, 0.f, 0.f, 0.f};
    gemm16_direct(actw, WjF, mI, quad, lane, acc);
#pragma unroll
    for (int ct = 0; ct < 8; ++ct) {
        float bb = bj_[ct * 16 + mI];
#pragma unroll
        for (int rg = 0; rg < 4; ++rg) {
            int r = rowrd + rg;
            if (r < NA) xj_out[(size_t)r * FD + ct * 16 + mI] = sspf(acc[ct][rg] + bb);
        }
    }
}

// whole post-scatter atom chain — ZERO barriers: act slices are wave-private,
// weights stream fragment-ordered from L2. TAIL fuses next block's pre.
template<bool TAIL>
__launch_bounds__(256, 4)
__global__ void chain_kernel(const float* __restrict__ xprev,
                             const float* __restrict__ mbuf,
                             const short* __restrict__ Wr1F, const float* __restrict__ br1_,
                             const short* __restrict__ Wr2F, const float* __restrict__ br2_,
                             const short* __restrict__ WoF,  const float* __restrict__ bo_,
                             const float* __restrict__ u_,
                             const short* __restrict__ Wf1F, const float* __restrict__ bf1_,
                             const short* __restrict__ Wf2F, const float* __restrict__ bf2_,
                             float* __restrict__ xout,
                             const short* __restrict__ WiF, const float* __restrict__ bi_,
                             const short* __restrict__ WjF, const float* __restrict__ bj_,
                             float* __restrict__ xi_out, float* __restrict__ xj_out)
{
    __shared__ short act_s[64 * 136];
    const int tid = threadIdx.x;
    const int lane = tid & 63, wv = tid >> 6;
    const int mI = lane & 15, quad = lane >> 4;
    short* actw = act_s + wv * 16 * 136;    // wave-private slice
    const int rowrd = blockIdx.x * 64 + wv * 16 + quad * 4;

    float mreg[8][4];
#pragma unroll
    for (int ct = 0; ct < 8; ++ct)
#pragma unroll
        for (int rg = 0; rg < 4; ++rg) {
            int r = rowrd + rg;
            mreg[ct][rg] = (r < NA) ? mbuf[(size_t)r * FD + ct * 16 + mI] : 0.f;
        }

    f32x4 acc[8];

    // ---- interaction residuals: m = m + ssp(ssp(m)@W1+b1)@W2 + b2 ----
    for (int r = 0; r < NRI_; ++r) {
#pragma unroll
        for (int ct = 0; ct < 8; ++ct)
#pragma unroll
            for (int rg = 0; rg < 4; ++rg)
                actw[(quad * 4 + rg) * 136 + ct * 16 + mI] = f2bf(sspf(mreg[ct][rg]));
#pragma unroll
        for (int ct = 0; ct < 8; ++ct) acc[ct] = (f32x4){0.f, 0.f, 0.f, 0.f};
        gemm16_direct(actw, Wr1F + (size_t)r * FD * FD, mI, quad, lane, acc);

#pragma unroll
        for (int ct = 0; ct < 8; ++ct) {
            float b1 = br1_[r * FD + ct * 16 + mI];
#pragma unroll
            for (int rg = 0; rg < 4; ++rg)
                actw[(quad * 4 + rg) * 136 + ct * 16 + mI] = f2bf(sspf(acc[ct][rg] + b1));
        }
#pragma unroll
        for (int ct = 0; ct < 8; ++ct) acc[ct] = (f32x4){0.f, 0.f, 0.f, 0.f};
        gemm16_direct(actw, Wr2F + (size_t)r * FD * FD, mI, quad, lane, acc);
#pragma unroll
        for (int ct = 0; ct < 8; ++ct) {
            float b2 = br2_[r * FD + ct * 16 + mI];
#pragma unroll
            for (int rg = 0; rg < 4; ++rg)
                mreg[ct][rg] += acc[ct][rg] + b2;
        }
    }

    // ---- gated update: x = u*xprev + ssp(m)@Wout + bout ----
#pragma unroll
    for (int ct = 0; ct < 8; ++ct)
#pragma unroll
        for (int rg = 0; rg < 4; ++rg)
            actw[(quad * 4 + rg) * 136 + ct * 16 + mI] = f2bf(sspf(mreg[ct][rg]));
#pragma unroll
    for (int ct = 0; ct < 8; ++ct) acc[ct] = (f32x4){0.f, 0.f, 0.f, 0.f};
    gemm16_direct(actw, WoF, mI, quad, lane, acc);

    float xreg[8][4];
#pragma unroll
    for (int ct = 0; ct < 8; ++ct) {
        float bo = bo_[ct * 16 + mI];
        float uu = u_[ct * 16 + mI];
#pragma unroll
        for (int rg = 0; rg < 4; ++rg) {
            int r = rowrd + rg;
            float xp = (r < NA) ? xprev[(size_t)r * FD + ct * 16 + mI] : 0.f;
            xreg[ct][rg] = fmaf(uu, xp, acc[ct][rg] + bo);
        }
    }

    // ---- feature residuals: x = x + ssp(ssp(x)@Wf1+bf1)@Wf2 + bf2 ----
    for (int r = 0; r < NRF_; ++r) {
#pragma unroll
        for (int ct = 0; ct < 8; ++ct)
#pragma unroll
            for (int rg = 0; rg < 4; ++rg)
                actw[(quad * 4 + rg) * 136 + ct * 16 + mI] = f2bf(sspf(xreg[ct][rg]));
#pragma unroll
        for (int ct = 0; ct < 8; ++ct) acc[ct] = (f32x4){0.f, 0.f, 0.f, 0.f};
        gemm16_direct(actw, Wf1F + (size_t)r * FD * FD, mI, quad, lane, acc);

#pragma unroll
        for (int ct = 0; ct < 8; ++ct) {
            float b1 = bf1_[r * FD + ct * 16 + mI];
#pragma unroll
            for (int rg = 0; rg < 4; ++rg)
                actw[(quad * 4 + rg) * 136 + ct * 16 + mI] = f2bf(sspf(acc[ct][rg] + b1));
        }
#pragma unroll
        for (int ct = 0; ct < 8; ++ct) acc[ct] = (f32x4){0.f, 0.f, 0.f, 0.f};
        gemm16_direct(actw, Wf2F + (size_t)r * FD * FD, mI, quad, lane, acc);
#pragma unroll
        for (int ct = 0; ct < 8; ++ct) {
            float b2 = bf2_[r * FD + ct * 16 + mI];
#pragma unroll
            for (int rg = 0; rg < 4; ++rg)
                xreg[ct][rg] += acc[ct][rg] + b2;
        }
    }

#pragma unroll
    for (int ct = 0; ct < 8; ++ct)
#pragma unroll
        for (int rg = 0; rg < 4; ++rg) {
            int r = rowrd + rg;
            if (r < NA) xout[(size_t)r * FD + ct * 16 + mI] = xreg[ct][rg];
        }

    // ---- fused pre of next block ----
    if constexpr (TAIL) {
#pragma unroll
        for (int ct = 0; ct < 8; ++ct)
#pragma unroll
            for (int rg = 0; rg < 4; ++rg)
                actw[(quad * 4 + rg) * 136 + ct * 16 + mI] = f2bf(sspf(xreg[ct][rg]));
#pragma unroll
        for (int ct = 0; ct < 8; ++ct) acc[ct] = (f32x4){0.f, 0.f, 0.f, 0.f};
        gemm16_direct(actw, WiF, mI, quad, lane, acc);
#pragma unroll
        for (int ct = 0; ct < 8; ++ct) {
            float bb = bi_[ct * 16 + mI];
#pragma unroll
            for (int rg = 0; rg < 4; ++rg) {
                int r = rowrd + rg;
                if (r < NA) xi_out[(size_t)r * FD + ct * 16 + mI] = sspf(acc[ct][rg] + bb);
            }
        }
#pragma unroll
        for (int ct = 0; ct < 8; ++ct) acc[ct] = (f32x4){0.f, 0.f, 0.f, 0.f};
        gemm16_direct(actw, WjF, mI, quad, lane, acc);
#pragma unroll
        for (int ct = 0; ct < 8; ++ct) {
            float bb = bj_[ct * 16 + mI];
#pragma unroll
            for (int rg = 0; rg < 4; ++rg) {
                int r = rowrd + rg;
                if (r < NA) xj_out[(size_t)r * FD + ct * 16 + mI] = sspf(acc[ct][rg] + bb);
            }
        }
    }
}

// g = desc @ Wg (MFMA, weights+A frag-ordered from global) ; msg = g * xj[idx_j] ; segment-sum
template<bool DESC>
__launch_bounds__(256, 4)
__global__ void pair_mfma(const float* __restrict__ rbfs,
                          const float* __restrict__ cutoffs,
                          const short* __restrict__ descF,  // frag-order (if DESC)
                          const int* __restrict__ idx_i,
                          const int* __restrict__ idx_j,
                          const short* __restrict__ WgF,    // frag-order [2][8][64][8]
                          const float* __restrict__ xj,
                          float* __restrict__ mout)
{
    __shared__ float g_s[64 * 132];
    __shared__ int ii_s[128];
    __shared__ int jj_s[128];

    const int tid = threadIdx.x;
    const long long p0 = (long long)blockIdx.x * 128;

    if (tid < 128) {
        long long pg = p0 + tid;
        ii_s[tid] = (pg < NP) ? idx_i[pg] : -1;
        jj_s[tid] = (pg < NP) ? idx_j[pg] : 0;
    }

    const int lane = tid & 63, wv = tid >> 6;
    const int m = lane & 15, quad = lane >> 4;

    f32x4 acc[2][8];
#pragma unroll
    for (int rt = 0; rt < 2; ++rt)
#pragma unroll
        for (int ct = 0; ct < 8; ++ct) acc[rt][ct] = (f32x4){0.f, 0.f, 0.f, 0.f};

#pragma unroll
    for (int chunk = 0; chunk < 2; ++chunk) {
        short8_t afr[2];
#pragma unroll
        for (int rt = 0; rt < 2; ++rt) {
            if constexpr (DESC) {
                long long tg = (long long)blockIdx.x * 8 + wv * 2 + rt;
                if (tg < (long long)NP / 16) {
                    afr[rt] = *(const short8_t*)&descF[((tg * 2 + chunk) * 64 + lane) * 8];
                } else {
                    int4 z = make_int4(0, 0, 0, 0);
                    afr[rt] = __builtin_bit_cast(short8_t, z);
                }
            } else {
                long long pg = p0 + wv * 32 + rt * 16 + m;
                float v[8];
                if (pg < NP) {
                    const float* ap = rbfs + pg * KD + chunk * 32 + quad * 8;
                    float4 x0 = *(const float4*)ap;
                    float4 x1 = *(const float4*)(ap + 4);
                    float cu = cutoffs[pg];
                    v[0] = x0.x * cu; v[1] = x0.y * cu; v[2] = x0.z * cu; v[3] = x0.w * cu;
                    v[4] = x1.x * cu; v[5] = x1.y * cu; v[6] = x1.z * cu; v[7] = x1.w * cu;
                } else {
#pragma unroll
                    for (int j = 0; j < 8; ++j) v[j] = 0.f;
                }
                int4 pk = make_int4((int)cvt_pk_bf16(v[0], v[1]),
                                    (int)cvt_pk_bf16(v[2], v[3]),
                                    (int)cvt_pk_bf16(v[4], v[5]),
                                    (int)cvt_pk_bf16(v[6], v[7]));
                afr[rt] = __builtin_bit_cast(short8_t, pk);
            }
        }
#pragma unroll
        for (int ct = 0; ct < 8; ++ct) {
            short8_t bfr = *(const short8_t*)&WgF[((chunk * 8 + ct) * 64 + lane) * 8];
            acc[0][ct] = __builtin_amdgcn_mfma_f32_16x16x32_bf16(afr[0], bfr, acc[0][ct], 0, 0, 0);
            acc[1][ct] = __builtin_amdgcn_mfma_f32_16x16x32_bf16(afr[1], bfr, acc[1][ct], 0, 0, 0);
        }
    }

    const int tx = tid & 15, ty = tid >> 4;
    const int c0 = tx * 4, c1 = c0 + 64;
    const int col = tid & 127, sh = tid >> 7;

#pragma unroll
    for (int h = 0; h < 2; ++h) {
        if ((wv >> 1) == h) {
#pragma unroll
            for (int ct = 0; ct < 8; ++ct) {
                int cg = ct * 16 + m;
#pragma unroll
                for (int rt = 0; rt < 2; ++rt) {
                    int lp = (wv & 1) * 32 + rt * 16 + quad * 4;
#pragma unroll
                    for (int rg = 0; rg < 4; ++rg)
                        g_s[(lp + rg) * 132 + cg] = acc[rt][ct][rg];
                }
            }
        }
        __syncthreads();                 // spill + ii/jj stage visible to all
#pragma unroll
        for (int i = 0; i < 4; ++i) {
            int p = ty + 16 * i;
            int jrow = jj_s[h * 64 + p];
            float4 xa = *(const float4*)&xj[(size_t)jrow * FD + c0];
            float4 xb = *(const float4*)&xj[(size_t)jrow * FD + c1];
            float4 ga = *(float4*)&g_s[p * 132 + c0];
            float4 gb = *(float4*)&g_s[p * 132 + c1];
            ga.x *= xa.x; ga.y *= xa.y; ga.z *= xa.z; ga.w *= xa.w;
            gb.x *= xb.x; gb.y *= xb.y; gb.z *= xb.z; gb.w *= xb.w;
            *(float4*)&g_s[p * 132 + c0] = ga;
            *(float4*)&g_s[p * 132 + c1] = gb;
        }
        __syncthreads();
        {
            int base = h * 64 + sh * 32;
            float accum = 0.f;
            int cur = ii_s[base];
            for (int q = 0; q < 32; ++q) {
                int a = ii_s[base + q];
                if (a != cur) {
                    if (cur >= 0) atomicAdd(&mout[(size_t)cur * FD + col], accum);
                    accum = 0.f;
                    cur = a;
                }
                accum += g_s[(sh * 32 + q) * 132 + col];
            }
            if (cur >= 0) atomicAdd(&mout[(size_t)cur * FD + col], accum);
        }
        if (h == 0) __syncthreads();
    }
}

extern "C" void kernel_launch(void* const* d_in, const int* in_sizes, int n_in,
                              void* d_out, int out_size, void* d_ws, size_t ws_size,
                              hipStream_t stream)
{
    const float* features = (const float*)d_in[0];
    const float* cutoffs  = (const float*)d_in[1];
    const float* rbfs     = (const float*)d_in[2];
    const int*   idx_i    = (const int*)d_in[3];
    const int*   idx_j    = (const int*)d_in[4];
    const float* Wg   = (const float*)d_in[5];
    const float* Wi   = (const float*)d_in[6];
    const float* bi   = (const float*)d_in[7];
    const float* Wj   = (const float*)d_in[8];
    const float* bj   = (const float*)d_in[9];
    const float* Wr1  = (const float*)d_in[10];
    const float* br1  = (const float*)d_in[11];
    const float* Wr2  = (const float*)d_in[12];
    const float* br2  = (const float*)d_in[13];
    const float* Wout = (const float*)d_in[14];
    const float* bout = (const float*)d_in[15];
    const float* u    = (const float*)d_in[16];
    const float* Wf1  = (const float*)d_in[17];
    const float* bf1  = (const float*)d_in[18];
    const float* Wf2  = (const float*)d_in[19];
    const float* bf2  = (const float*)d_in[20];
    float* out = (float*)d_out;

    const size_t NF = (size_t)NA * FD;
    const size_t MS = (size_t)FD * FD;
    float* mbuf = (float*)d_ws;
    short* wtb  = (short*)(mbuf + NF);
    short* wgt  = wtb + 65 * MS;
    short* desc = wgt + (size_t)NB * FD * KD;
    float* xjbuf = out + 4 * NF;            // out[4] slice: free until b=4's chain write

    const size_t base_bytes = NF * 4 + 65 * MS * 2 + (size_t)NB * FD * KD * 2;
    const size_t desc_bytes = (size_t)NP * KD * 2;
    const bool use_desc = ws_size >= base_bytes + desc_bytes;

    frag_weights<<<5,  256, 0, stream>>>(Wi,   wtb +  0 * MS, 4);
    frag_weights<<<5,  256, 0, stream>>>(Wj,   wtb +  5 * MS, 4);
    frag_weights<<<15, 256, 0, stream>>>(Wr1,  wtb + 10 * MS, 4);
    frag_weights<<<15, 256, 0, stream>>>(Wr2,  wtb + 25 * MS, 4);
    frag_weights<<<5,  256, 0, stream>>>(Wout, wtb + 40 * MS, 4);
    frag_weights<<<10, 256, 0, stream>>>(Wf1,  wtb + 45 * MS, 4);
    frag_weights<<<10, 256, 0, stream>>>(Wf2,  wtb + 55 * MS, 4);
    frag_weights<<<5,  256, 0, stream>>>(Wg,   wgt, 2);
    if (use_desc) {
        prep_desc<<<(int)(((long long)NP * 8 + 255) / 256), 256, 0, stream>>>(rbfs, cutoffs, desc);
    }

    const int gA = (NA + 63) / 64;          // 782
    const int gP = (NP + 127) / 128;        // 7813
    dim3 blk(256);

    // b = 0: standalone pre (x = features)
    pre_kernel<<<gA, blk, 0, stream>>>(features,
        wtb + 0 * MS, bi, wtb + 5 * MS, bj, mbuf, xjbuf);

    const float* x = features;
    for (int b = 0; b < NB; ++b) {
        float* xout = out + (size_t)b * NF;

        if (use_desc) {
            pair_mfma<true><<<gP, blk, 0, stream>>>(rbfs, cutoffs, desc, idx_i, idx_j,
                wgt + (size_t)b * FD * KD, xjbuf, mbuf);
        } else {
            pair_mfma<false><<<gP, blk, 0, stream>>>(rbfs, cutoffs, desc, idx_i, idx_j,
                wgt + (size_t)b * FD * KD, xjbuf, mbuf);
        }

        if (b < NB - 1) {
            chain_kernel<true><<<gA, blk, 0, stream>>>(x, mbuf,
                wtb + (10 + b * NRI_) * MS, br1 + (size_t)b * NRI_ * FD,
                wtb + (25 + b * NRI_) * MS, br2 + (size_t)b * NRI_ * FD,
                wtb + (40 + b) * MS, bout + (size_t)b * FD, u + (size_t)b * FD,
                wtb + (45 + b * NRF_) * MS, bf1 + (size_t)b * NRF_ * FD,
                wtb + (55 + b * NRF_) * MS, bf2 + (size_t)b * NRF_ * FD,
                xout,
                wtb + (0 + (b + 1)) * MS, bi + (size_t)(b + 1) * FD,
                wtb + (5 + (b + 1)) * MS, bj + (size_t)(b + 1) * FD,
                mbuf, xjbuf);
        } else {
            chain_kernel<false><<<gA, blk, 0, stream>>>(x, mbuf,
                wtb + (10 + b * NRI_) * MS, br1 + (size_t)b * NRI_ * FD,
                wtb + (25 + b * NRI_) * MS, br2 + (size_t)b * NRI_ * FD,
                wtb + (40 + b) * MS, bout + (size_t)b * FD, u + (size_t)b * FD,
                wtb + (45 + b * NRF_) * MS, bf1 + (size_t)b * NRF_ * FD,
                wtb + (55 + b * NRF_) * MS, bf2 + (size_t)b * NRF_ * FD,
                xout,
                (const short*)nullptr, (const float*)nullptr,
                (const short*)nullptr, (const float*)nullptr,
                (float*)nullptr, (float*)nullptr);
        }
        x = xout;
    }
}